// Round 15
// baseline (454.955 us; speedup 1.0000x reference)
//
#include <hip/hip_runtime.h>
#include <hip/hip_bf16.h>
#include <cstdint>

typedef __attribute__((ext_vector_type(4))) float f32x4;
typedef __attribute__((ext_vector_type(8))) short bf16x8;
typedef __attribute__((ext_vector_type(8))) unsigned short u16x8;

__device__ inline unsigned short f2bf(float f) {
    union { float f; unsigned u; } v; v.f = f;
    unsigned r = v.u + 0x7FFFu + ((v.u >> 16) & 1u);
    return (unsigned short)(r >> 16);
}
__device__ inline float bf2f(unsigned short h) {
    union { unsigned u; float f; } v; v.u = ((unsigned)h) << 16;
    return v.f;
}

// ---------------------------------------------------------------- prep
// WnT [272][64] c-major: c<64 Wl | 64..127 Wa1^T | 128..159 WV |
//   160..191 Ww1 | 192 bav1 | 193..207 pad0 | 208..271 I(64)
// WeX [176][64]: c<64 We | 64..95 Ww2 | 96..159 Wa2^T | 160 bav2 | pad0
__global__ void prep_kernel(
    const float* __restrict__ We,
    const float* __restrict__ Wul, const float* __restrict__ Wau, const float* __restrict__ WVu,
    const float* __restrict__ Wvl, const float* __restrict__ Wav, const float* __restrict__ WVv,
    const float* __restrict__ Wwu, const float* __restrict__ Wwv,
    const float* __restrict__ bul, const float* __restrict__ bau, const float* __restrict__ bVu,
    const float* __restrict__ bvl, const float* __restrict__ bav, const float* __restrict__ bVv,
    unsigned short* __restrict__ WeXf, unsigned short* __restrict__ WeXb,
    unsigned short* __restrict__ WnTu, unsigned short* __restrict__ WnTv,
    float* __restrict__ bcu, float* __restrict__ bcv)
{
    int tid0 = blockIdx.x * blockDim.x + threadIdx.x;
    int stride = gridDim.x * blockDim.x;
    for (int i = tid0; i < 176 * 64; i += stride) {
        int c = i >> 6, k = i & 63;
        float vf, vb;
        if (c < 64)       { vf = We[k * 64 + c];               vb = vf; }
        else if (c < 96)  { vf = Wwv[(64 + k) * 32 + (c - 64)]; vb = Wwu[(64 + k) * 32 + (c - 64)]; }
        else if (c < 160) { vf = Wav[(c - 96) * 128 + 64 + k];  vb = Wau[(c - 96) * 128 + 64 + k]; }
        else if (c == 160){ vf = bav[64 + k];                   vb = bau[64 + k]; }
        else              { vf = 0.f;                           vb = 0.f; }
        WeXf[i] = f2bf(vf);
        WeXb[i] = f2bf(vb);
    }
    for (int i = tid0; i < 272 * 64; i += stride) {
        int c = i >> 6, k = i & 63;
        float vu, vv;
        if (c < 64)       { vu = Wul[k * 64 + c];           vv = Wvl[k * 64 + c]; }
        else if (c < 128) { vu = Wav[(c - 64) * 128 + k];   vv = Wau[(c - 64) * 128 + k]; }
        else if (c < 160) { vu = WVu[k * 32 + (c - 128)];   vv = WVv[k * 32 + (c - 128)]; }
        else if (c < 192) { vu = Wwv[k * 32 + (c - 160)];   vv = Wwu[k * 32 + (c - 160)]; }
        else if (c == 192){ vu = bav[k];                    vv = bau[k]; }
        else if (c < 208) { vu = 0.f;                       vv = 0.f; }
        else              { vu = (k == c - 208) ? 1.f : 0.f; vv = vu; }
        WnTu[i] = f2bf(vu);
        WnTv[i] = f2bf(vv);
    }
    for (int i = tid0; i < 208; i += stride) {
        float u = 0.f, v = 0.f;
        if (i < 64)                { u = bul[i];       v = bvl[i]; }
        else if (i >= 128 && i < 160) { u = bVu[i - 128]; v = bVv[i - 128]; }
        bcu[i] = u; bcv[i] = v;
    }
}

// ---------------------------------------------------------------- node pre (merged u/v):
// [64 nodes/block] feat@[Wl|Wa1^T|WV|Ww1|bav1|I] (K=64, N=272)
// Interleaved permuted tables (per node, 128 shorts each):
//   srcT[n][lrow*8 + 0..3] = z cols (tt*16+lrow);  +4..7 = he cols
//   dstT[n][lrow*8 + 0..3] = nbf cols;             +4..7 = he cols
__global__ __launch_bounds__(256, 4) void node_pre_kernel(
    int nbU, int NU, int NV,
    const float* __restrict__ featU, const float* __restrict__ featV,
    const unsigned short* __restrict__ WTu, const unsigned short* __restrict__ WTv,
    const float* __restrict__ bcu, const float* __restrict__ bcv,
    unsigned short* __restrict__ srcTU, unsigned short* __restrict__ srcTV,
    unsigned short* __restrict__ dstTU, unsigned short* __restrict__ dstTV,
    float* __restrict__ outU, float* __restrict__ outV,
    unsigned short* __restrict__ projU, unsigned short* __restrict__ projV,
    float* __restrict__ sbU, float* __restrict__ sbV,
    float* __restrict__ aggU, float* __restrict__ aggV,
    float* __restrict__ wsU, float* __restrict__ wsV)
{
    bool isu = (int)blockIdx.x < nbU;
    int blk = isu ? blockIdx.x : blockIdx.x - nbU;
    int N = isu ? NU : NV;
    const float* feat = isu ? featU : featV;
    const unsigned short* WT = isu ? WTu : WTv;
    const float* bc = isu ? bcu : bcv;
    unsigned short* srcT = isu ? srcTU : srcTV;
    unsigned short* dstT = isu ? dstTU : dstTV;
    float* outp = isu ? outU : outV;
    unsigned short* proj = isu ? projU : projV;
    float* sb = isu ? sbU : sbV;
    float* agg32 = isu ? aggU : aggV;
    float* ws = isu ? wsU : wsV;

    __shared__ unsigned short lW[272 * 64];   // 34 KB
    int tid = threadIdx.x;
    int n0 = blk * 64;

    const uint4* wsrc = (const uint4*)WT;
    for (int i = tid; i < 272 * 8; i += 256) {
        int r = i >> 3, ch = i & 7;
        *(uint4*)&lW[r * 64 + ((ch ^ (r & 7)) << 3)] = wsrc[i];
    }
    {   // zero agg32 + ws
        for (int i = tid; i < 64 * 32; i += 256) {
            int n = n0 + (i >> 5);
            if (n < N) agg32[(size_t)n * 32 + (i & 31)] = 0.f;
        }
        if (tid < 64) { int n = n0 + tid; if (n < N) ws[n] = 0.f; }
    }

    int wv = tid >> 6, lane = tid & 63;
    int r0 = wv * 16;
    int lrow = lane & 15, lkg = lane >> 4;

    int nr = n0 + r0 + lrow;
    bool rok = nr < N;
    const float* arow = &feat[(size_t)nr * 64];
    bf16x8 a[2];
    #pragma unroll
    for (int h = 0; h < 2; ++h) {
        int ch = h * 4 + lkg;
        f32x4 v0 = (f32x4){0.f, 0.f, 0.f, 0.f}, v1 = v0;
        if (rok) {
            v0 = __builtin_nontemporal_load((const f32x4*)&arow[ch * 8]);
            v1 = __builtin_nontemporal_load((const f32x4*)&arow[ch * 8 + 4]);
        }
        bf16x8 av;
        av[0] = (short)f2bf(v0.x); av[1] = (short)f2bf(v0.y);
        av[2] = (short)f2bf(v0.z); av[3] = (short)f2bf(v0.w);
        av[4] = (short)f2bf(v1.x); av[5] = (short)f2bf(v1.y);
        av[6] = (short)f2bf(v1.z); av[7] = (short)f2bf(v1.w);
        a[h] = av;
    }
    __syncthreads();

    f32x4 acc[17];
    #pragma unroll
    for (int t = 0; t < 17; ++t) acc[t] = (f32x4){0.f, 0.f, 0.f, 0.f};
    #pragma unroll
    for (int t = 0; t < 17; ++t) {
        int row = t * 16 + lrow;
        #pragma unroll
        for (int h = 0; h < 2; ++h) {
            int ch = h * 4 + lkg;
            bf16x8 b = *(const bf16x8*)&lW[row * 64 + ((ch ^ (row & 7)) << 3)];
            acc[t] = __builtin_amdgcn_mfma_f32_16x16x32_bf16(a[h], b, acc[t], 0, 0, 0);
        }
    }
    #pragma unroll
    for (int t = 0; t < 17; ++t) {
        #pragma unroll
        for (int q = 0; q < 4; ++q) {
            int n = n0 + r0 + lkg * 4 + q;
            if (n >= N) continue;
            int c = t * 16 + lrow;
            float raw = acc[t][q];
            if (t < 4) {
                unsigned short hv = f2bf(raw + bc[c]);
                srcT[(size_t)n * 128 + lrow * 8 + 4 + t] = hv;
                dstT[(size_t)n * 128 + lrow * 8 + 4 + t] = hv;
            } else if (t < 8) {
                srcT[(size_t)n * 128 + lrow * 8 + (t - 4)] = f2bf(raw);
            } else if (t < 10) {
                __builtin_nontemporal_store(raw + bc[c], &outp[(size_t)n * 64 + (c - 128)]);
            } else if (t < 12) {
                proj[(size_t)n * 32 + (c - 160)] = f2bf(raw);
            } else if (t == 12) {
                if (lrow == 0) sb[n] = raw;
            } else {
                dstT[(size_t)n * 128 + lrow * 8 + (t - 13)] = f2bf(raw);
            }
        }
    }
}

// ---------------------------------------------------------------- edge (merged fwd/bwd):
// [64 edges/block] GEMM e@[We|Ww2|Wa2^T|bav2] (K=64, N=176).
// One u16x8 (16B) gather per side per edge fetches BOTH score half (z/nbf)
// and store half (he). Phases: score -> out_he store -> atomics.
__global__ __launch_bounds__(256, 5) void edge_kernel(
    int nbF, int EF, int EB,
    const float* __restrict__ efF, const float* __restrict__ efB,
    const int* __restrict__ srcF, const int* __restrict__ dstF,
    const int* __restrict__ srcB, const int* __restrict__ dstB,
    const unsigned short* __restrict__ srcTU, const unsigned short* __restrict__ srcTV,
    const unsigned short* __restrict__ dstTU, const unsigned short* __restrict__ dstTV,
    const float* __restrict__ sbF, const float* __restrict__ sbB,
    const unsigned short* __restrict__ projF, const unsigned short* __restrict__ projB,
    const unsigned short* __restrict__ WeXF, const unsigned short* __restrict__ WeXB,
    const float* __restrict__ be,
    float* __restrict__ outF, float* __restrict__ outB,
    float* __restrict__ aggF, float* __restrict__ aggB,
    float* __restrict__ wsF, float* __restrict__ wsB)
{
    bool fwd = (int)blockIdx.x < nbF;
    int blk = fwd ? blockIdx.x : blockIdx.x - nbF;
    int E = fwd ? EF : EB;
    const float* efeat = fwd ? efF : efB;
    const int* src = fwd ? srcF : srcB;
    const int* dst = fwd ? dstF : dstB;
    const unsigned short* srcT = fwd ? srcTU : srcTV;   // src-side: z|he
    const unsigned short* dstT = fwd ? dstTV : dstTU;   // dst-side: nbf|he
    const float* sb_src = fwd ? sbF : sbB;
    const unsigned short* proj_src = fwd ? projF : projB;
    const unsigned short* WeX = fwd ? WeXF : WeXB;
    float* out_he = fwd ? outF : outB;
    float* agg32 = fwd ? aggF : aggB;
    float* wsum = fwd ? wsF : wsB;

    __shared__ unsigned short lW[176 * 64];   // 22 KB
    int tid = threadIdx.x;
    int lane = tid & 63;
    int wvu = __builtin_amdgcn_readfirstlane(tid >> 6);
    int e0 = blk * 64;
    int eBase = e0 + wvu * 16;
    int lrow = lane & 15, lkg = lane >> 4;

    const uint4* wsrc = (const uint4*)WeX;
    for (int i = tid; i < 176 * 8; i += 256) {
        int r = i >> 3, ch = i & 7;
        *(uint4*)&lW[r * 64 + ((ch ^ (r & 7)) << 3)] = wsrc[i];
    }

    // per-lane-group edge indices (group lkg owns rows lkg*4+j)
    int sil[4], dil[4];
    #pragma unroll
    for (int j = 0; j < 4; ++j) {
        int e = eBase + lkg * 4 + j;
        sil[j] = (e < E) ? src[e] : 0;
        dil[j] = (e < E) ? dst[e] : 0;
    }

    // A fragments in-register from global f32 (row eBase+lrow), nontemporal
    int er = eBase + lrow;
    bool rok = er < E;
    const float* arow = &efeat[(size_t)er * 64];
    bf16x8 a[2];
    #pragma unroll
    for (int h = 0; h < 2; ++h) {
        int ch = h * 4 + lkg;
        f32x4 v0 = (f32x4){0.f, 0.f, 0.f, 0.f}, v1 = v0;
        if (rok) {
            v0 = __builtin_nontemporal_load((const f32x4*)&arow[ch * 8]);
            v1 = __builtin_nontemporal_load((const f32x4*)&arow[ch * 8 + 4]);
        }
        bf16x8 av;
        av[0] = (short)f2bf(v0.x); av[1] = (short)f2bf(v0.y);
        av[2] = (short)f2bf(v0.z); av[3] = (short)f2bf(v0.w);
        av[4] = (short)f2bf(v1.x); av[5] = (short)f2bf(v1.y);
        av[6] = (short)f2bf(v1.z); av[7] = (short)f2bf(v1.w);
        a[h] = av;
    }
    __syncthreads();   // lW ready (the only barrier)

    f32x4 acc[11];
    #pragma unroll
    for (int t = 0; t < 11; ++t) acc[t] = (f32x4){0.f, 0.f, 0.f, 0.f};
    #pragma unroll
    for (int t = 0; t < 11; ++t) {
        int row = t * 16 + lrow;
        #pragma unroll
        for (int h = 0; h < 2; ++h) {
            int ch = h * 4 + lkg;
            bf16x8 b = *(const bf16x8*)&lW[row * 64 + ((ch ^ (row & 7)) << 3)];
            acc[t] = __builtin_amdgcn_mfma_f32_16x16x32_bf16(a[h], b, acc[t], 0, 0, 0);
        }
    }

    // ---- score phase: ONE 16B load per side per edge (z|he, nbf|he)
    u16x8 sr_[4], dr_[4];
    float wq[4];
    #pragma unroll
    for (int j = 0; j < 4; ++j) {
        int e = eBase + lkg * 4 + j;
        int si = sil[j], di = dil[j];
        sr_[j] = *(const u16x8*)&srcT[(size_t)si * 128 + lrow * 8];
        dr_[j] = *(const u16x8*)&dstT[(size_t)di * 128 + lrow * 8];
        float p = acc[10][j];   // sbe at col 160 (lrow==0); cols 161+ zero
        if (e < E) {
            #pragma unroll
            for (int tt = 0; tt < 4; ++tt) {
                float zv = bf2f(sr_[j][tt]) + acc[6 + tt][j];
                p += zv * bf2f(dr_[j][tt]);
            }
            if (lrow == 1) p += sb_src[si];
        }
        p += __shfl_xor(p, 1, 64);
        p += __shfl_xor(p, 2, 64);
        p += __shfl_xor(p, 4, 64);
        p += __shfl_xor(p, 8, 64);
        wq[j] = __expf(p);
    }

    // ---- out_he store: fragment layout; he halves already in sr_/dr_
    float bev[4];
    #pragma unroll
    for (int t = 0; t < 4; ++t) bev[t] = be[t * 16 + lrow];
    #pragma unroll
    for (int q = 0; q < 4; ++q) {
        int e = eBase + lkg * 4 + q;
        if (e >= E) continue;
        #pragma unroll
        for (int t = 0; t < 4; ++t) {
            int c = t * 16 + lrow;
            __builtin_nontemporal_store(
                acc[t][q] + bev[t] + bf2f(sr_[q][4 + t]) + bf2f(dr_[q][4 + t]),
                &out_he[(size_t)e * 64 + c]);
        }
    }

    // ---- atomic phase (proj2 = acc[4],acc[5] in-register; proj table bf16)
    #pragma unroll
    for (int j = 0; j < 4; ++j) {
        int e = eBase + lkg * 4 + j;
        if (e >= E) continue;
        float w = wq[j];
        int si = sil[j], di = dil[j];
        #pragma unroll
        for (int h = 0; h < 2; ++h) {
            int c = lrow + h * 16;
            float pv = bf2f(proj_src[(size_t)si * 32 + c]) + acc[4 + h][j];
            unsafeAtomicAdd(&agg32[(size_t)di * 32 + c], w * pv);
        }
        if (lrow == 2) unsafeAtomicAdd(&wsum[di], w);
    }
}

// ---------------------------------------------------------------- finalize (merged):
__global__ void finalize_kernel(const float* __restrict__ aggU, const float* __restrict__ wsU,
                                const float* __restrict__ aggV, const float* __restrict__ wsV,
                                int NU, int NV,
                                const float* __restrict__ bwu, const float* __restrict__ bwv,
                                float* __restrict__ outU, float* __restrict__ outV)
{
    int idx = blockIdx.x * blockDim.x + threadIdx.x;
    int tot = (NU + NV) * 32;
    if (idx >= tot) return;
    bool isu = idx < NU * 32;
    int li = isu ? idx : idx - NU * 32;
    int n = li >> 5, c = li & 31;
    const float* agg = isu ? aggU : aggV;
    const float* ws = isu ? wsU : wsV;
    const float* bias = isu ? bwu : bwv;
    float* outp = isu ? outU : outV;
    float s = ws[n];
    float sc = (s > 0.f) ? 1.0f / s : 0.f;
    __builtin_nontemporal_store(agg[li] * sc + bias[c], &outp[(size_t)n * 64 + 32 + c]);
}

// ---------------------------------------------------------------- launch
extern "C" void kernel_launch(void* const* d_in, const int* in_sizes, int n_in,
                              void* d_out, int out_size, void* d_ws, size_t ws_size,
                              hipStream_t stream)
{
    const float* f_feat = (const float*)d_in[0];
    const float* b_feat = (const float*)d_in[1];
    const float* u_feat = (const float*)d_in[2];
    const float* v_feat = (const float*)d_in[3];
    const int* fsrc = (const int*)d_in[4];
    const int* fdst = (const int*)d_in[5];
    const int* bsrc = (const int*)d_in[6];
    const int* bdst = (const int*)d_in[7];
    const float* We  = (const float*)d_in[8];
    const float* be  = (const float*)d_in[9];
    const float* Wul = (const float*)d_in[10];
    const float* bul = (const float*)d_in[11];
    const float* Wvl = (const float*)d_in[12];
    const float* bvl = (const float*)d_in[13];
    const float* Wau = (const float*)d_in[14];
    const float* bau = (const float*)d_in[15];
    const float* Wav = (const float*)d_in[16];
    const float* bav = (const float*)d_in[17];
    const float* Wwu = (const float*)d_in[18];
    const float* bwu = (const float*)d_in[19];
    const float* Wwv = (const float*)d_in[20];
    const float* bwv = (const float*)d_in[21];
    const float* WVu = (const float*)d_in[22];
    const float* bVu = (const float*)d_in[23];
    const float* WVv = (const float*)d_in[24];
    const float* bVv = (const float*)d_in[25];

    int EF = in_sizes[0] / 64;
    int EB = in_sizes[1] / 64;
    int NU = in_sizes[2] / 64;
    int NV = in_sizes[3] / 64;

    float* out = (float*)d_out;
    float* hf = out;
    float* hb = hf + (size_t)EF * 64;
    float* hu = hb + (size_t)EB * 64;
    float* hv = hu + (size_t)NU * 64;

    char* wp = (char*)d_ws;
    auto alloc = [&](size_t bytes) { char* p = wp; wp += (bytes + 255) & ~(size_t)255; return p; };
    unsigned short* srcT_u = (unsigned short*)alloc((size_t)NU * 128 * 2);
    unsigned short* srcT_v = (unsigned short*)alloc((size_t)NV * 128 * 2);
    unsigned short* dstT_u = (unsigned short*)alloc((size_t)NU * 128 * 2);
    unsigned short* dstT_v = (unsigned short*)alloc((size_t)NV * 128 * 2);
    unsigned short* proj_u = (unsigned short*)alloc((size_t)NU * 32 * 2);
    unsigned short* proj_v = (unsigned short*)alloc((size_t)NV * 32 * 2);
    float* sb_u   = (float*)alloc((size_t)NU * 4);
    float* sb_v   = (float*)alloc((size_t)NV * 4);
    float* agg_u  = (float*)alloc((size_t)NU * 32 * 4);
    float* agg_v  = (float*)alloc((size_t)NV * 32 * 4);
    float* ws_u   = (float*)alloc((size_t)NU * 4);
    float* ws_v   = (float*)alloc((size_t)NV * 4);
    unsigned short* WeXf = (unsigned short*)alloc(176 * 64 * 2);
    unsigned short* WeXb = (unsigned short*)alloc(176 * 64 * 2);
    unsigned short* WnTu = (unsigned short*)alloc(272 * 64 * 2);
    unsigned short* WnTv = (unsigned short*)alloc(272 * 64 * 2);
    float* bcu = (float*)alloc(208 * 4);
    float* bcv = (float*)alloc(208 * 4);

    prep_kernel<<<64, 256, 0, stream>>>(We, Wul, Wau, WVu, Wvl, Wav, WVv, Wwu, Wwv,
                                        bul, bau, bVu, bvl, bav, bVv,
                                        WeXf, WeXb, WnTu, WnTv, bcu, bcv);

    int nbU = (NU + 63) / 64, nbV = (NV + 63) / 64;
    node_pre_kernel<<<nbU + nbV, 256, 0, stream>>>(nbU, NU, NV, u_feat, v_feat,
                                                   WnTu, WnTv, bcu, bcv,
                                                   srcT_u, srcT_v, dstT_u, dstT_v,
                                                   hu, hv, proj_u, proj_v, sb_u, sb_v,
                                                   agg_u, agg_v, ws_u, ws_v);

    int nbF = (EF + 63) / 64, nbB = (EB + 63) / 64;
    edge_kernel<<<nbF + nbB, 256, 0, stream>>>(nbF, EF, EB, f_feat, b_feat,
                                               fsrc, fdst, bsrc, bdst,
                                               srcT_u, srcT_v, dstT_u, dstT_v,
                                               sb_u, sb_v, proj_u, proj_v,
                                               WeXf, WeXb, be,
                                               hf, hb, agg_v, agg_u, ws_v, ws_u);

    finalize_kernel<<<((NU + NV) * 32 + 255) / 256, 256, 0, stream>>>(
        agg_u, ws_u, agg_v, ws_v, NU, NV, bwu, bwv, hu, hv);
}

// Round 16
// 342.891 us; speedup vs baseline: 1.3268x; 1.3268x over previous
//
#include <hip/hip_runtime.h>
#include <hip/hip_bf16.h>
#include <cstdint>

typedef __attribute__((ext_vector_type(4))) float f32x4;
typedef __attribute__((ext_vector_type(8))) short bf16x8;
typedef __attribute__((ext_vector_type(4))) unsigned short u16x4;

__device__ inline unsigned short f2bf(float f) {
    union { float f; unsigned u; } v; v.f = f;
    unsigned r = v.u + 0x7FFFu + ((v.u >> 16) & 1u);
    return (unsigned short)(r >> 16);
}
__device__ inline float bf2f(unsigned short h) {
    union { unsigned u; float f; } v; v.u = ((unsigned)h) << 16;
    return v.f;
}

// ---------------------------------------------------------------- prep
// WnT [272][64] c-major: c<64 Wl | 64..127 Wa1^T | 128..159 WV |
//   160..191 Ww1 | 192 bav1 | 193..207 pad0 | 208..271 I(64)
// WeX [176][64]: c<64 We | 64..95 Ww2 | 96..159 Wa2^T | 160 bav2 | pad0
__global__ void prep_kernel(
    const float* __restrict__ We,
    const float* __restrict__ Wul, const float* __restrict__ Wau, const float* __restrict__ WVu,
    const float* __restrict__ Wvl, const float* __restrict__ Wav, const float* __restrict__ WVv,
    const float* __restrict__ Wwu, const float* __restrict__ Wwv,
    const float* __restrict__ bul, const float* __restrict__ bau, const float* __restrict__ bVu,
    const float* __restrict__ bvl, const float* __restrict__ bav, const float* __restrict__ bVv,
    unsigned short* __restrict__ WeXf, unsigned short* __restrict__ WeXb,
    unsigned short* __restrict__ WnTu, unsigned short* __restrict__ WnTv,
    float* __restrict__ bcu, float* __restrict__ bcv)
{
    int tid0 = blockIdx.x * blockDim.x + threadIdx.x;
    int stride = gridDim.x * blockDim.x;
    for (int i = tid0; i < 176 * 64; i += stride) {
        int c = i >> 6, k = i & 63;
        float vf, vb;
        if (c < 64)       { vf = We[k * 64 + c];               vb = vf; }
        else if (c < 96)  { vf = Wwv[(64 + k) * 32 + (c - 64)]; vb = Wwu[(64 + k) * 32 + (c - 64)]; }
        else if (c < 160) { vf = Wav[(c - 96) * 128 + 64 + k];  vb = Wau[(c - 96) * 128 + 64 + k]; }
        else if (c == 160){ vf = bav[64 + k];                   vb = bau[64 + k]; }
        else              { vf = 0.f;                           vb = 0.f; }
        WeXf[i] = f2bf(vf);
        WeXb[i] = f2bf(vb);
    }
    for (int i = tid0; i < 272 * 64; i += stride) {
        int c = i >> 6, k = i & 63;
        float vu, vv;
        if (c < 64)       { vu = Wul[k * 64 + c];           vv = Wvl[k * 64 + c]; }
        else if (c < 128) { vu = Wav[(c - 64) * 128 + k];   vv = Wau[(c - 64) * 128 + k]; }
        else if (c < 160) { vu = WVu[k * 32 + (c - 128)];   vv = WVv[k * 32 + (c - 128)]; }
        else if (c < 192) { vu = Wwv[k * 32 + (c - 160)];   vv = Wwu[k * 32 + (c - 160)]; }
        else if (c == 192){ vu = bav[k];                    vv = bau[k]; }
        else if (c < 208) { vu = 0.f;                       vv = 0.f; }
        else              { vu = (k == c - 208) ? 1.f : 0.f; vv = vu; }
        WnTu[i] = f2bf(vu);
        WnTv[i] = f2bf(vv);
    }
    for (int i = tid0; i < 208; i += stride) {
        float u = 0.f, v = 0.f;
        if (i < 64)                { u = bul[i];       v = bvl[i]; }
        else if (i >= 128 && i < 160) { u = bVu[i - 128]; v = bVv[i - 128]; }
        bcu[i] = u; bcv[i] = v;
    }
}

// ---------------------------------------------------------------- node pre (merged u/v):
// [64 nodes/block] feat@[Wl|Wa1^T|WV|Ww1|bav1|I] (K=64, N=272)
// he/z/nbf written PERMUTED: tbl[n][lrow*4+t] = orig[n][t*16+lrow]; proj bf16
__global__ __launch_bounds__(256, 4) void node_pre_kernel(
    int nbU, int NU, int NV,
    const float* __restrict__ featU, const float* __restrict__ featV,
    const unsigned short* __restrict__ WTu, const unsigned short* __restrict__ WTv,
    const float* __restrict__ bcu, const float* __restrict__ bcv,
    unsigned short* __restrict__ heU, unsigned short* __restrict__ heV,
    unsigned short* __restrict__ ztU, unsigned short* __restrict__ ztV,
    unsigned short* __restrict__ nbfU, unsigned short* __restrict__ nbfV,
    float* __restrict__ outU, float* __restrict__ outV,
    unsigned short* __restrict__ projU, unsigned short* __restrict__ projV,
    float* __restrict__ sbU, float* __restrict__ sbV,
    float* __restrict__ aggU, float* __restrict__ aggV,
    float* __restrict__ wsU, float* __restrict__ wsV)
{
    bool isu = (int)blockIdx.x < nbU;
    int blk = isu ? blockIdx.x : blockIdx.x - nbU;
    int N = isu ? NU : NV;
    const float* feat = isu ? featU : featV;
    const unsigned short* WT = isu ? WTu : WTv;
    const float* bc = isu ? bcu : bcv;
    unsigned short* he = isu ? heU : heV;
    unsigned short* zt = isu ? ztU : ztV;
    unsigned short* nbf = isu ? nbfU : nbfV;
    float* outp = isu ? outU : outV;
    unsigned short* proj = isu ? projU : projV;
    float* sb = isu ? sbU : sbV;
    float* agg32 = isu ? aggU : aggV;
    float* ws = isu ? wsU : wsV;

    __shared__ unsigned short lW[272 * 64];   // 34 KB
    int tid = threadIdx.x;
    int n0 = blk * 64;

    const uint4* wsrc = (const uint4*)WT;
    for (int i = tid; i < 272 * 8; i += 256) {
        int r = i >> 3, ch = i & 7;
        *(uint4*)&lW[r * 64 + ((ch ^ (r & 7)) << 3)] = wsrc[i];
    }
    {   // zero agg32 + ws
        for (int i = tid; i < 64 * 32; i += 256) {
            int n = n0 + (i >> 5);
            if (n < N) agg32[(size_t)n * 32 + (i & 31)] = 0.f;
        }
        if (tid < 64) { int n = n0 + tid; if (n < N) ws[n] = 0.f; }
    }

    int wv = tid >> 6, lane = tid & 63;
    int r0 = wv * 16;
    int lrow = lane & 15, lkg = lane >> 4;

    int nr = n0 + r0 + lrow;
    bool rok = nr < N;
    const float* arow = &feat[(size_t)nr * 64];
    bf16x8 a[2];
    #pragma unroll
    for (int h = 0; h < 2; ++h) {
        int ch = h * 4 + lkg;
        f32x4 v0 = (f32x4){0.f, 0.f, 0.f, 0.f}, v1 = v0;
        if (rok) {
            v0 = __builtin_nontemporal_load((const f32x4*)&arow[ch * 8]);
            v1 = __builtin_nontemporal_load((const f32x4*)&arow[ch * 8 + 4]);
        }
        bf16x8 av;
        av[0] = (short)f2bf(v0.x); av[1] = (short)f2bf(v0.y);
        av[2] = (short)f2bf(v0.z); av[3] = (short)f2bf(v0.w);
        av[4] = (short)f2bf(v1.x); av[5] = (short)f2bf(v1.y);
        av[6] = (short)f2bf(v1.z); av[7] = (short)f2bf(v1.w);
        a[h] = av;
    }
    __syncthreads();

    f32x4 acc[17];
    #pragma unroll
    for (int t = 0; t < 17; ++t) acc[t] = (f32x4){0.f, 0.f, 0.f, 0.f};
    #pragma unroll
    for (int t = 0; t < 17; ++t) {
        int row = t * 16 + lrow;
        #pragma unroll
        for (int h = 0; h < 2; ++h) {
            int ch = h * 4 + lkg;
            bf16x8 b = *(const bf16x8*)&lW[row * 64 + ((ch ^ (row & 7)) << 3)];
            acc[t] = __builtin_amdgcn_mfma_f32_16x16x32_bf16(a[h], b, acc[t], 0, 0, 0);
        }
    }
    #pragma unroll
    for (int t = 0; t < 17; ++t) {
        #pragma unroll
        for (int q = 0; q < 4; ++q) {
            int n = n0 + r0 + lkg * 4 + q;
            if (n >= N) continue;
            int c = t * 16 + lrow;
            float raw = acc[t][q];
            if (t < 4) {
                he[(size_t)n * 64 + lrow * 4 + t] = f2bf(raw + bc[c]);
            } else if (t < 8) {
                zt[(size_t)n * 64 + lrow * 4 + (t - 4)] = f2bf(raw);
            } else if (t < 10) {
                __builtin_nontemporal_store(raw + bc[c], &outp[(size_t)n * 64 + (c - 128)]);
            } else if (t < 12) {
                proj[(size_t)n * 32 + (c - 160)] = f2bf(raw);
            } else if (t == 12) {
                if (lrow == 0) sb[n] = raw;
            } else {
                nbf[(size_t)n * 64 + lrow * 4 + (t - 13)] = f2bf(raw);
            }
        }
    }
}

// ---------------------------------------------------------------- edge (merged fwd/bwd):
// [64 edges/block] GEMM e@[We|Ww2|Wa2^T|bav2] split into two phases so the
// accumulator peak is 24 AGPR (not 44):
//   GEMM-1 rows 96..175 (ze+sbe, 5 tiles) -> score -> sched_barrier
//   GEMM-2 rows 0..95 (he+proj2, 6 tiles) -> store -> atomics
// (256,6): ~50 VGPR + 24 AGPR <= 85 budget; LDS 22.5KB*6=135<=160.
__global__ __launch_bounds__(256, 6) void edge_kernel(
    int nbF, int EF, int EB,
    const float* __restrict__ efF, const float* __restrict__ efB,
    const int* __restrict__ srcF, const int* __restrict__ dstF,
    const int* __restrict__ srcB, const int* __restrict__ dstB,
    const unsigned short* __restrict__ zF, const unsigned short* __restrict__ zB,
    const float* __restrict__ sbF, const float* __restrict__ sbB,
    const unsigned short* __restrict__ projF, const unsigned short* __restrict__ projB,
    const unsigned short* __restrict__ heSF, const unsigned short* __restrict__ heSB,
    const unsigned short* __restrict__ heDF, const unsigned short* __restrict__ heDB,
    const unsigned short* __restrict__ nbfF, const unsigned short* __restrict__ nbfB,
    const unsigned short* __restrict__ WeXF, const unsigned short* __restrict__ WeXB,
    const float* __restrict__ be,
    float* __restrict__ outF, float* __restrict__ outB,
    float* __restrict__ aggF, float* __restrict__ aggB,
    float* __restrict__ wsF, float* __restrict__ wsB)
{
    bool fwd = (int)blockIdx.x < nbF;
    int blk = fwd ? blockIdx.x : blockIdx.x - nbF;
    int E = fwd ? EF : EB;
    const float* efeat = fwd ? efF : efB;
    const int* src = fwd ? srcF : srcB;
    const int* dst = fwd ? dstF : dstB;
    const unsigned short* z_src = fwd ? zF : zB;
    const float* sb_src = fwd ? sbF : sbB;
    const unsigned short* proj_src = fwd ? projF : projB;
    const unsigned short* he_src = fwd ? heSF : heSB;
    const unsigned short* he_dst = fwd ? heDF : heDB;
    const unsigned short* nbf_dst = fwd ? nbfF : nbfB;
    const unsigned short* WeX = fwd ? WeXF : WeXB;
    float* out_he = fwd ? outF : outB;
    float* agg32 = fwd ? aggF : aggB;
    float* wsum = fwd ? wsF : wsB;

    __shared__ unsigned short lW[176 * 64];   // 22 KB
    int tid = threadIdx.x;
    int lane = tid & 63;
    int wvu = __builtin_amdgcn_readfirstlane(tid >> 6);
    int e0 = blk * 64;
    int eBase = e0 + wvu * 16;
    int lrow = lane & 15, lkg = lane >> 4;

    const uint4* wsrc = (const uint4*)WeX;
    for (int i = tid; i < 176 * 8; i += 256) {
        int r = i >> 3, ch = i & 7;
        *(uint4*)&lW[r * 64 + ((ch ^ (r & 7)) << 3)] = wsrc[i];
    }

    // per-lane-group edge indices (group lkg owns rows lkg*4+j)
    int sil[4], dil[4];
    #pragma unroll
    for (int j = 0; j < 4; ++j) {
        int e = eBase + lkg * 4 + j;
        sil[j] = (e < E) ? src[e] : 0;
        dil[j] = (e < E) ? dst[e] : 0;
    }

    // A fragments in-register from global f32 (row eBase+lrow), nontemporal
    int er = eBase + lrow;
    bool rok = er < E;
    const float* arow = &efeat[(size_t)er * 64];
    bf16x8 a[2];
    #pragma unroll
    for (int h = 0; h < 2; ++h) {
        int ch = h * 4 + lkg;
        f32x4 v0 = (f32x4){0.f, 0.f, 0.f, 0.f}, v1 = v0;
        if (rok) {
            v0 = __builtin_nontemporal_load((const f32x4*)&arow[ch * 8]);
            v1 = __builtin_nontemporal_load((const f32x4*)&arow[ch * 8 + 4]);
        }
        bf16x8 av;
        av[0] = (short)f2bf(v0.x); av[1] = (short)f2bf(v0.y);
        av[2] = (short)f2bf(v0.z); av[3] = (short)f2bf(v0.w);
        av[4] = (short)f2bf(v1.x); av[5] = (short)f2bf(v1.y);
        av[6] = (short)f2bf(v1.z); av[7] = (short)f2bf(v1.w);
        a[h] = av;
    }
    __syncthreads();   // lW ready (the only barrier)

    // ---- GEMM-1: tiles t=6..10 (ze rows 96..159, sbe row 160)
    f32x4 accS[5];
    #pragma unroll
    for (int t = 0; t < 5; ++t) accS[t] = (f32x4){0.f, 0.f, 0.f, 0.f};
    #pragma unroll
    for (int t = 0; t < 5; ++t) {
        int row = (t + 6) * 16 + lrow;
        #pragma unroll
        for (int h = 0; h < 2; ++h) {
            int ch = h * 4 + lkg;
            bf16x8 b = *(const bf16x8*)&lW[row * 64 + ((ch ^ (row & 7)) << 3)];
            accS[t] = __builtin_amdgcn_mfma_f32_16x16x32_bf16(a[h], b, accS[t], 0, 0, 0);
        }
    }

    // ---- score phase: one 8B row-load per table per edge
    float wq[4];
    #pragma unroll
    for (int j = 0; j < 4; ++j) {
        int e = eBase + lkg * 4 + j;
        float p = accS[4][j];   // sbe at col 160 (lrow==0); cols 161+ zero
        if (e < E) {
            int si = sil[j], di = dil[j];
            u16x4 zr = *(const u16x4*)&z_src[(size_t)si * 64 + lrow * 4];
            u16x4 vr = *(const u16x4*)&nbf_dst[(size_t)di * 64 + lrow * 4];
            #pragma unroll
            for (int tt = 0; tt < 4; ++tt) {
                float zv = bf2f(zr[tt]) + accS[tt][j];
                p += zv * bf2f(vr[tt]);
            }
            if (lrow == 1) p += sb_src[si];
        }
        p += __shfl_xor(p, 1, 64);
        p += __shfl_xor(p, 2, 64);
        p += __shfl_xor(p, 4, 64);
        p += __shfl_xor(p, 8, 64);
        wq[j] = __expf(p);
    }
    __builtin_amdgcn_sched_barrier(0);   // keep GEMM-2 below the score (accS dead here)

    // ---- GEMM-2: tiles t=0..5 (he rows 0..63, proj2 rows 64..95)
    f32x4 accH[6];
    #pragma unroll
    for (int t = 0; t < 6; ++t) accH[t] = (f32x4){0.f, 0.f, 0.f, 0.f};
    #pragma unroll
    for (int t = 0; t < 6; ++t) {
        int row = t * 16 + lrow;
        #pragma unroll
        for (int h = 0; h < 2; ++h) {
            int ch = h * 4 + lkg;
            bf16x8 b = *(const bf16x8*)&lW[row * 64 + ((ch ^ (row & 7)) << 3)];
            accH[t] = __builtin_amdgcn_mfma_f32_16x16x32_bf16(a[h], b, accH[t], 0, 0, 0);
        }
    }

    // ---- out_he store: fragment layout, he gathers as 8B row-loads
    float bev[4];
    #pragma unroll
    for (int t = 0; t < 4; ++t) bev[t] = be[t * 16 + lrow];
    #pragma unroll
    for (int q = 0; q < 4; ++q) {
        int e = eBase + lkg * 4 + q;
        if (e >= E) continue;
        int si = sil[q], di = dil[q];
        u16x4 hs4 = *(const u16x4*)&he_src[(size_t)si * 64 + lrow * 4];
        u16x4 hd4 = *(const u16x4*)&he_dst[(size_t)di * 64 + lrow * 4];
        #pragma unroll
        for (int t = 0; t < 4; ++t) {
            int c = t * 16 + lrow;
            __builtin_nontemporal_store(accH[t][q] + bev[t] + bf2f(hs4[t]) + bf2f(hd4[t]),
                                        &out_he[(size_t)e * 64 + c]);
        }
    }

    // ---- atomic phase (proj2 = accH[4],accH[5]; proj table bf16)
    #pragma unroll
    for (int j = 0; j < 4; ++j) {
        int e = eBase + lkg * 4 + j;
        if (e >= E) continue;
        float w = wq[j];
        int si = sil[j], di = dil[j];
        #pragma unroll
        for (int h = 0; h < 2; ++h) {
            int c = lrow + h * 16;
            float pv = bf2f(proj_src[(size_t)si * 32 + c]) + accH[4 + h][j];
            unsafeAtomicAdd(&agg32[(size_t)di * 32 + c], w * pv);
        }
        if (lrow == 2) unsafeAtomicAdd(&wsum[di], w);
    }
}

// ---------------------------------------------------------------- finalize (merged):
__global__ void finalize_kernel(const float* __restrict__ aggU, const float* __restrict__ wsU,
                                const float* __restrict__ aggV, const float* __restrict__ wsV,
                                int NU, int NV,
                                const float* __restrict__ bwu, const float* __restrict__ bwv,
                                float* __restrict__ outU, float* __restrict__ outV)
{
    int idx = blockIdx.x * blockDim.x + threadIdx.x;
    int tot = (NU + NV) * 32;
    if (idx >= tot) return;
    bool isu = idx < NU * 32;
    int li = isu ? idx : idx - NU * 32;
    int n = li >> 5, c = li & 31;
    const float* agg = isu ? aggU : aggV;
    const float* ws = isu ? wsU : wsV;
    const float* bias = isu ? bwu : bwv;
    float* outp = isu ? outU : outV;
    float s = ws[n];
    float sc = (s > 0.f) ? 1.0f / s : 0.f;
    __builtin_nontemporal_store(agg[li] * sc + bias[c], &outp[(size_t)n * 64 + 32 + c]);
}

// ---------------------------------------------------------------- launch
extern "C" void kernel_launch(void* const* d_in, const int* in_sizes, int n_in,
                              void* d_out, int out_size, void* d_ws, size_t ws_size,
                              hipStream_t stream)
{
    const float* f_feat = (const float*)d_in[0];
    const float* b_feat = (const float*)d_in[1];
    const float* u_feat = (const float*)d_in[2];
    const float* v_feat = (const float*)d_in[3];
    const int* fsrc = (const int*)d_in[4];
    const int* fdst = (const int*)d_in[5];
    const int* bsrc = (const int*)d_in[6];
    const int* bdst = (const int*)d_in[7];
    const float* We  = (const float*)d_in[8];
    const float* be  = (const float*)d_in[9];
    const float* Wul = (const float*)d_in[10];
    const float* bul = (const float*)d_in[11];
    const float* Wvl = (const float*)d_in[12];
    const float* bvl = (const float*)d_in[13];
    const float* Wau = (const float*)d_in[14];
    const float* bau = (const float*)d_in[15];
    const float* Wav = (const float*)d_in[16];
    const float* bav = (const float*)d_in[17];
    const float* Wwu = (const float*)d_in[18];
    const float* bwu = (const float*)d_in[19];
    const float* Wwv = (const float*)d_in[20];
    const float* bwv = (const float*)d_in[21];
    const float* WVu = (const float*)d_in[22];
    const float* bVu = (const float*)d_in[23];
    const float* WVv = (const float*)d_in[24];
    const float* bVv = (const float*)d_in[25];

    int EF = in_sizes[0] / 64;
    int EB = in_sizes[1] / 64;
    int NU = in_sizes[2] / 64;
    int NV = in_sizes[3] / 64;

    float* out = (float*)d_out;
    float* hf = out;
    float* hb = hf + (size_t)EF * 64;
    float* hu = hb + (size_t)EB * 64;
    float* hv = hu + (size_t)NU * 64;

    char* wp = (char*)d_ws;
    auto alloc = [&](size_t bytes) { char* p = wp; wp += (bytes + 255) & ~(size_t)255; return p; };
    unsigned short* he_u  = (unsigned short*)alloc((size_t)NU * 64 * 2);
    unsigned short* he_v  = (unsigned short*)alloc((size_t)NV * 64 * 2);
    unsigned short* z_u   = (unsigned short*)alloc((size_t)NU * 64 * 2);
    unsigned short* z_v   = (unsigned short*)alloc((size_t)NV * 64 * 2);
    unsigned short* nbf_u = (unsigned short*)alloc((size_t)NU * 64 * 2);
    unsigned short* nbf_v = (unsigned short*)alloc((size_t)NV * 64 * 2);
    unsigned short* proj_u = (unsigned short*)alloc((size_t)NU * 32 * 2);
    unsigned short* proj_v = (unsigned short*)alloc((size_t)NV * 32 * 2);
    float* sb_u   = (float*)alloc((size_t)NU * 4);
    float* sb_v   = (float*)alloc((size_t)NV * 4);
    float* agg_u  = (float*)alloc((size_t)NU * 32 * 4);
    float* agg_v  = (float*)alloc((size_t)NV * 32 * 4);
    float* ws_u   = (float*)alloc((size_t)NU * 4);
    float* ws_v   = (float*)alloc((size_t)NV * 4);
    unsigned short* WeXf = (unsigned short*)alloc(176 * 64 * 2);
    unsigned short* WeXb = (unsigned short*)alloc(176 * 64 * 2);
    unsigned short* WnTu = (unsigned short*)alloc(272 * 64 * 2);
    unsigned short* WnTv = (unsigned short*)alloc(272 * 64 * 2);
    float* bcu = (float*)alloc(208 * 4);
    float* bcv = (float*)alloc(208 * 4);

    prep_kernel<<<64, 256, 0, stream>>>(We, Wul, Wau, WVu, Wvl, Wav, WVv, Wwu, Wwv,
                                        bul, bau, bVu, bvl, bav, bVv,
                                        WeXf, WeXb, WnTu, WnTv, bcu, bcv);

    int nbU = (NU + 63) / 64, nbV = (NV + 63) / 64;
    node_pre_kernel<<<nbU + nbV, 256, 0, stream>>>(nbU, NU, NV, u_feat, v_feat,
                                                   WnTu, WnTv, bcu, bcv,
                                                   he_u, he_v, z_u, z_v, nbf_u, nbf_v,
                                                   hu, hv, proj_u, proj_v, sb_u, sb_v,
                                                   agg_u, agg_v, ws_u, ws_v);

    int nbF = (EF + 63) / 64, nbB = (EB + 63) / 64;
    edge_kernel<<<nbF + nbB, 256, 0, stream>>>(nbF, EF, EB, f_feat, b_feat,
                                               fsrc, fdst, bsrc, bdst,
                                               z_u, z_v, sb_u, sb_v, proj_u, proj_v,
                                               he_u, he_v, he_v, he_u,
                                               nbf_v, nbf_u,
                                               WeXf, WeXb, be,
                                               hf, hb, agg_v, agg_u, ws_v, ws_u);

    finalize_kernel<<<((NU + NV) * 32 + 255) / 256, 256, 0, stream>>>(
        agg_u, ws_u, agg_v, ws_v, NU, NV, bwu, bwv, hu, hv);
}